// Round 5
// baseline (35526.355 us; speedup 1.0000x reference)
//
#include <hip/hip_runtime.h>
#include <stdint.h>

// ---------------------------------------------------------------------------
// LIDM forward, round 5: custom split-phase two-level barrier (replaces
// cg::grid.sync), 8x-deduplicated noise panels in global (triple-buffered,
// flag-released), noise-GEMM + V-gen overlapped with barrier latency.
// ---------------------------------------------------------------------------
#define S_ 256
#define B_ 64
#define O_ 128
#define L_ 256
#define NL_ 25

typedef __attribute__((ext_vector_type(8))) short short8v;
typedef __attribute__((ext_vector_type(16))) float f32x16;

// ---- workspace byte offsets ----
#define SH_B    0u          // u16: e1 temp / Hlast [256][256][64]
#define EMLP_B  8388608u    // u16 [256][64][256]
#define HST_B   16777216u   // u16 [2][25][64][256]
#define CST_B   18415616u   // f32 [25][256][64]
#define WF_B    20054016u   // u16 [25][1024][256]
#define BIASF_B 33161216u   // f32 [25][1024]
#define VBUF_B  33263616u   // u16 [3][25][64][256]
#define VFLAG_B 35721216u   // u32 [25][257] + pad + bar[16]  (6448 words)
#define BAR_B   35746944u   // u32 [16]: [0..7]=group cnt, [8]=root
#define WS_END  35747008u

// ---------------------------- helpers --------------------------------------
__device__ __forceinline__ uint16_t f2bf(float x) {
  uint32_t u = __float_as_uint(x);
  return (uint16_t)((u + 0x7fffu + ((u >> 16) & 1u)) >> 16);
}
__device__ __forceinline__ float bf2f(uint16_t u) {
  return __uint_as_float(((uint32_t)u) << 16);
}
__device__ __forceinline__ short8v pack8(float4 a, float4 b) {
  short8v w;
  w[0] = (short)f2bf(a.x); w[1] = (short)f2bf(a.y);
  w[2] = (short)f2bf(a.z); w[3] = (short)f2bf(a.w);
  w[4] = (short)f2bf(b.x); w[5] = (short)f2bf(b.y);
  w[6] = (short)f2bf(b.z); w[7] = (short)f2bf(b.w);
  return w;
}

__device__ __forceinline__ uint32_t rotl32(uint32_t v, int r) {
  return (v << r) | (v >> (32 - r));
}

__device__ __forceinline__ void tf2x32(uint32_t k0, uint32_t k1,
                                       uint32_t x0, uint32_t x1,
                                       uint32_t& o0, uint32_t& o1) {
  uint32_t ks2 = k0 ^ k1 ^ 0x1BD11BDAu;
  x0 += k0; x1 += k1;
  x0 += x1; x1 = rotl32(x1, 13); x1 ^= x0;
  x0 += x1; x1 = rotl32(x1, 15); x1 ^= x0;
  x0 += x1; x1 = rotl32(x1, 26); x1 ^= x0;
  x0 += x1; x1 = rotl32(x1,  6); x1 ^= x0;
  x0 += k1; x1 += ks2 + 1u;
  x0 += x1; x1 = rotl32(x1, 17); x1 ^= x0;
  x0 += x1; x1 = rotl32(x1, 29); x1 ^= x0;
  x0 += x1; x1 = rotl32(x1, 16); x1 ^= x0;
  x0 += x1; x1 = rotl32(x1, 24); x1 ^= x0;
  x0 += ks2; x1 += k0 + 2u;
  x0 += x1; x1 = rotl32(x1, 13); x1 ^= x0;
  x0 += x1; x1 = rotl32(x1, 15); x1 ^= x0;
  x0 += x1; x1 = rotl32(x1, 26); x1 ^= x0;
  x0 += x1; x1 = rotl32(x1,  6); x1 ^= x0;
  x0 += k0; x1 += k1 + 3u;
  x0 += x1; x1 = rotl32(x1, 17); x1 ^= x0;
  x0 += x1; x1 = rotl32(x1, 29); x1 ^= x0;
  x0 += x1; x1 = rotl32(x1, 16); x1 ^= x0;
  x0 += x1; x1 = rotl32(x1, 24); x1 ^= x0;
  x0 += k1; x1 += ks2 + 4u;
  x0 += x1; x1 = rotl32(x1, 13); x1 ^= x0;
  x0 += x1; x1 = rotl32(x1, 15); x1 ^= x0;
  x0 += x1; x1 = rotl32(x1, 26); x1 ^= x0;
  x0 += x1; x1 = rotl32(x1,  6); x1 ^= x0;
  o0 = x0 + ks2; o1 = x1 + k0 + 5u;
}

__device__ __forceinline__ void step_keys(int k, uint32_t& kh0, uint32_t& kh1,
                                          uint32_t& kx0, uint32_t& kx1) {
  uint32_t f0, f1;
  tf2x32(0u, 42u, 0u, (uint32_t)k, f0, f1);
  tf2x32(f0, f1, 0u, 0u, kh0, kh1);
  tf2x32(f0, f1, 0u, 1u, kx0, kx1);
}

__device__ __forceinline__ uint32_t rbits(uint32_t key0, uint32_t key1,
                                          uint32_t i) {
  uint32_t b0, b1;
  tf2x32(key0, key1, 0u, i, b0, b1);
  return b0 ^ b1;
}

__device__ __forceinline__ float u32_to_normal(uint32_t bits) {
  const float lo = __uint_as_float(0xBF7FFFFFu);
  float f = __uint_as_float((bits >> 9) | 0x3F800000u) - 1.0f;
  float u = f * 2.0f + lo;
  u = fmaxf(lo, u);
  float x = u;
  float w = -log1pf(-x * x);
  float p;
  if (w < 5.0f) {
    w -= 2.5f;
    p =            2.81022636e-08f;
    p = fmaf(p, w, 3.43273939e-07f);
    p = fmaf(p, w, -3.5233877e-06f);
    p = fmaf(p, w, -4.39150654e-06f);
    p = fmaf(p, w, 0.00021858087f);
    p = fmaf(p, w, -0.00125372503f);
    p = fmaf(p, w, -0.00417768164f);
    p = fmaf(p, w, 0.246640727f);
    p = fmaf(p, w, 1.50140941f);
  } else {
    w = sqrtf(w) - 3.0f;
    p =            -0.000200214257f;
    p = fmaf(p, w, 0.000100950558f);
    p = fmaf(p, w, 0.00134934322f);
    p = fmaf(p, w, -0.00367342844f);
    p = fmaf(p, w, 0.00573950773f);
    p = fmaf(p, w, -0.0076224613f);
    p = fmaf(p, w, 0.00943887047f);
    p = fmaf(p, w, 1.00167406f);
    p = fmaf(p, w, 2.83297682f);
  }
  return __uint_as_float(0x3FB504F3u) * (p * x);
}

__device__ __forceinline__ float sigm(float x) { return 1.0f / (1.0f + expf(-x)); }

// ---------------------- barrier / flag primitives --------------------------
__device__ __forceinline__ void bar_arrive(uint32_t* bar, int grp, uint32_t gen) {
  __syncthreads();
  if (threadIdx.x == 0) {
    __threadfence();
    uint32_t old = __hip_atomic_fetch_add(&bar[grp], 1u, __ATOMIC_RELEASE,
                                          __HIP_MEMORY_SCOPE_AGENT);
    if (old + 1u == 25u * gen)
      __hip_atomic_fetch_add(&bar[8], 1u, __ATOMIC_RELEASE,
                             __HIP_MEMORY_SCOPE_AGENT);
  }
}
__device__ __forceinline__ void bar_wait(uint32_t* bar, uint32_t gen) {
  if (threadIdx.x == 0) {
    while (__hip_atomic_load(&bar[8], __ATOMIC_ACQUIRE,
                             __HIP_MEMORY_SCOPE_AGENT) < 8u * gen)
      __builtin_amdgcn_s_sleep(2);
  }
  __syncthreads();
  __threadfence();
}

// generate this block's 1/8 chunk of noise panel V_l(step), publish + flag
__device__ __forceinline__ void gen_V(uint16_t* vbuf, uint32_t* vflag,
                                      int l, int s, int step, int t) {
  uint32_t kh0, kh1, kx0, kx1;
  step_keys(step, kh0, kh1, kx0, kx1);
  int b = t >> 3;
  int j0 = s * 32 + (t & 7) * 4;
  uint32_t ib = ((uint32_t)(l * 64 + b)) * 256 + (uint32_t)j0;
  uint16_t v[4];
#pragma unroll
  for (int q = 0; q < 4; ++q)
    v[q] = f2bf(0.1f * u32_to_normal(rbits(kh0, kh1, ib + q)));
  uint16_t* dst = vbuf + ((size_t)((step % 3) * NL_ + l) << 14) + b * 256 + j0;
  *reinterpret_cast<uint2*>(dst) = *reinterpret_cast<const uint2*>(v);
  __syncthreads();
  if (t == 0) {
    __threadfence();
    __hip_atomic_fetch_add(&vflag[l * 257 + step], 1u, __ATOMIC_RELEASE,
                           __HIP_MEMORY_SCOPE_AGENT);
  }
}

// ------------------------------- prep kernels ------------------------------
__global__ __launch_bounds__(256) void k_init(const float* __restrict__ z0,
                                              uint16_t* __restrict__ hs0,
                                              float* __restrict__ c_state,
                                              uint32_t* __restrict__ zbase) {
  int idx = blockIdx.x * 256 + threadIdx.x;
  hs0[idx] = f2bf(z0[idx]);
  c_state[idx] = 0.0f;
  if (idx < 6448) zbase[idx] = 0u;   // vflag + pad + barrier counters
}

__global__ __launch_bounds__(256) void k_wf(const float* __restrict__ Whh,
                                            const float* __restrict__ Wemb,
                                            uint16_t* __restrict__ Wf) {
  __shared__ float Bs[32][256];
  int l = blockIdx.x >> 4, rt = blockIdx.x & 15;
  int j = threadIdx.x;
  float acc[64];
#pragma unroll
  for (int r = 0; r < 64; ++r) acc[r] = 0.0f;
  const float* Abase = Whh + ((size_t)l * 1024 + rt * 64) * 256;
  for (int m0 = 0; m0 < 256; m0 += 32) {
    __syncthreads();
    {
      int rr = threadIdx.x >> 3, cseg = threadIdx.x & 7;
      const float* src = Wemb + (size_t)(m0 + rr) * 256 + cseg * 32;
      float* dst = &Bs[rr][cseg * 32];
#pragma unroll
      for (int q = 0; q < 8; ++q)
        reinterpret_cast<float4*>(dst)[q] = reinterpret_cast<const float4*>(src)[q];
    }
    __syncthreads();
    for (int mm = 0; mm < 32; ++mm) {
      float bj = Bs[mm][j];
      const float* Acol = Abase + m0 + mm;
#pragma unroll
      for (int r = 0; r < 64; ++r) acc[r] = fmaf(Acol[r * 256], bj, acc[r]);
    }
  }
  for (int r = 0; r < 64; ++r)
    Wf[((size_t)l * 1024 + rt * 64 + r) * 256 + j] = f2bf(acc[r]);
}

__global__ __launch_bounds__(256) void k_biasf(const float* __restrict__ Whh,
                                               const float* __restrict__ bemb,
                                               const float* __restrict__ bih,
                                               const float* __restrict__ bhh,
                                               float* __restrict__ biasf) {
  int l = blockIdx.x >> 2;
  int gi = (blockIdx.x & 3) * 256 + threadIdx.x;
  const float* row = Whh + ((size_t)l * 1024 + gi) * 256;
  float a = 0.0f;
  for (int m = 0; m < 256; ++m) a = fmaf(row[m], bemb[m], a);
  biasf[l * 1024 + gi] = a + bih[l * 1024 + gi] + bhh[l * 1024 + gi];
}

__global__ __launch_bounds__(256) void k_mlp1(const float* __restrict__ obsrv,
                                              const float* __restrict__ Wx1,
                                              const float* __restrict__ bx1,
                                              uint16_t* __restrict__ e1out) {
  int k = 1 + (blockIdx.x >> 2);
  int jc = blockIdx.x & 3;
  int lane = threadIdx.x & 63;
  int wv = threadIdx.x >> 6;
  int j0 = jc * 64 + wv * 16;
  const float* xrow = obsrv + ((size_t)k * B_ + lane) * O_;
  float acc[16];
#pragma unroll
  for (int i = 0; i < 16; ++i) acc[i] = 0.0f;
  for (int o = 0; o < O_; o += 4) {
    float4 a = *reinterpret_cast<const float4*>(&xrow[o]);
#pragma unroll
    for (int mi = 0; mi < 16; ++mi) {
      float4 wt = *reinterpret_cast<const float4*>(&Wx1[(size_t)(j0 + mi) * O_ + o]);
      float t = acc[mi];
      t = fmaf(a.x, wt.x, t); t = fmaf(a.y, wt.y, t);
      t = fmaf(a.z, wt.z, t); t = fmaf(a.w, wt.w, t);
      acc[mi] = t;
    }
  }
  uint16_t* dst = e1out + (size_t)k * L_ * B_;
#pragma unroll
  for (int mi = 0; mi < 16; ++mi) {
    float v = acc[mi] + bx1[j0 + mi];
    dst[(j0 + mi) * B_ + lane] = f2bf(fmaxf(v, 0.0f));
  }
}

__global__ __launch_bounds__(256) void k_mlp2(const uint16_t* __restrict__ e1buf,
                                              const float* __restrict__ Wx2,
                                              const float* __restrict__ bx2,
                                              const float* __restrict__ Wx3,
                                              const float* __restrict__ bx3,
                                              uint16_t* __restrict__ E_mlp) {
  __shared__ float e2s[L_ * B_];
  int k = 1 + blockIdx.x;
  int lane = threadIdx.x & 63;
  int wv = threadIdx.x >> 6;
  const uint16_t* e1 = e1buf + (size_t)k * L_ * B_;

  for (int rep = 0; rep < 4; ++rep) {
    int m0 = rep * 64 + wv * 16;
    float acc[16];
#pragma unroll
    for (int i = 0; i < 16; ++i) acc[i] = 0.0f;
    for (int j = 0; j < L_; j += 4) {
      float a0 = bf2f(e1[(j + 0) * B_ + lane]);
      float a1 = bf2f(e1[(j + 1) * B_ + lane]);
      float a2 = bf2f(e1[(j + 2) * B_ + lane]);
      float a3 = bf2f(e1[(j + 3) * B_ + lane]);
#pragma unroll
      for (int mi = 0; mi < 16; ++mi) {
        float4 wt = *reinterpret_cast<const float4*>(&Wx2[(size_t)(m0 + mi) * L_ + j]);
        float t = acc[mi];
        t = fmaf(a0, wt.x, t); t = fmaf(a1, wt.y, t);
        t = fmaf(a2, wt.z, t); t = fmaf(a3, wt.w, t);
        acc[mi] = t;
      }
    }
#pragma unroll
    for (int mi = 0; mi < 16; ++mi) {
      float v = acc[mi] + bx2[m0 + mi];
      e2s[(m0 + mi) * B_ + lane] = fmaxf(v, 0.0f);
    }
  }
  __syncthreads();

  uint32_t kh0, kh1, kx0, kx1;
  step_keys(k, kh0, kh1, kx0, kx1);
  const float sa = sqrtf(0.9f);

  for (int rep = 0; rep < 4; ++rep) {
    int m0 = rep * 64 + wv * 16;
    float acc[16];
#pragma unroll
    for (int i = 0; i < 16; ++i) acc[i] = 0.0f;
    for (int j = 0; j < L_; j += 4) {
      float a0 = e2s[(j + 0) * B_ + lane];
      float a1 = e2s[(j + 1) * B_ + lane];
      float a2 = e2s[(j + 2) * B_ + lane];
      float a3 = e2s[(j + 3) * B_ + lane];
#pragma unroll
      for (int mi = 0; mi < 16; ++mi) {
        float4 wt = *reinterpret_cast<const float4*>(&Wx3[(size_t)(m0 + mi) * L_ + j]);
        float t = acc[mi];
        t = fmaf(a0, wt.x, t); t = fmaf(a1, wt.y, t);
        t = fmaf(a2, wt.z, t); t = fmaf(a3, wt.w, t);
        acc[mi] = t;
      }
    }
    uint16_t tmp[16];
#pragma unroll
    for (int mi = 0; mi < 16; ++mi) {
      int m = m0 + mi;
      float nz = u32_to_normal(rbits(kx0, kx1, (uint32_t)(lane * L_ + m)));
      tmp[mi] = f2bf(sa * (acc[mi] + bx3[m]) + 0.1f * nz);
    }
    uint16_t* dst = E_mlp + ((size_t)k * B_ + lane) * L_ + m0;
    *reinterpret_cast<uint4*>(dst) = *reinterpret_cast<const uint4*>(&tmp[0]);
    *reinterpret_cast<uint4*>(dst + 8) = *reinterpret_cast<const uint4*>(&tmp[8]);
  }
}

// ------------------------------ wavefront ----------------------------------
// 200 blocks x 512 thr; block = (l = bid>>3, s = bid&7); LDS 131072 B.
__global__ __launch_bounds__(512, 1) void k_wave(
    const uint16_t* __restrict__ Wf, const float* __restrict__ W_ih,
    const float* __restrict__ W_hh, const float* __restrict__ biasf,
    uint16_t* __restrict__ hstate, const uint16_t* __restrict__ emlp,
    float* __restrict__ cstate, uint16_t* __restrict__ hlast,
    uint16_t* __restrict__ vbuf, uint32_t* __restrict__ vflag,
    uint32_t* __restrict__ bar) {
  __shared__ __align__(16) unsigned char WAF[65536];  // Wf slice, swizzled
  __shared__ __align__(16) unsigned char WAI[65536];  // W_ih slice, swizzled

  const int bid = blockIdx.x;
  const int l = bid >> 3;
  const int s = bid & 7;
  const int grp = bid / 25;
  const int t = threadIdx.x;
  const int lane = t & 63;
  const int wid = t >> 6;
  const int lo5 = lane & 31;
  const int hi = lane >> 5;
  const int tm = wid >> 1;
  const int tn = wid & 1;
  const int bcol = tn * 32 + lo5;
  const int arow = tm * 32 + lo5;
  const int aswz = (arow & 7) << 4;
  const int gi_a = (arow & 3) * 256 + s * 32 + (arow >> 5) * 8 + ((arow >> 2) & 7);

  // pack Wf (bf16) and W_ih (f32->bf16) slices into LDS, XOR-swizzled
  for (int it = 0; it < 8; ++it) {
    int c = it * 512 + t;
    int r = c >> 5, cc = c & 31;
    int gi = (r & 3) * 256 + s * 32 + (r >> 5) * 8 + ((r >> 2) & 7);
    uint4 v = *reinterpret_cast<const uint4*>(Wf + ((size_t)l * 1024 + gi) * 256 + cc * 8);
    *reinterpret_cast<uint4*>(WAF + r * 512 + ((cc * 16) ^ ((r & 7) << 4))) = v;
  }
  for (int it = 0; it < 8; ++it) {
    int c = it * 512 + t;
    int r = c >> 5, cc = c & 31;
    int gi = (r & 3) * 256 + s * 32 + (r >> 5) * 8 + ((r >> 2) & 7);
    const float* sr = W_ih + ((size_t)l * 1024 + gi) * 256 + cc * 8;
    float4 f0 = *reinterpret_cast<const float4*>(sr);
    float4 f1 = *reinterpret_cast<const float4*>(sr + 4);
    *reinterpret_cast<short8v*>(WAI + r * 512 + ((cc * 16) ^ ((r & 7) << 4))) = pack8(f0, f1);
  }
  __syncthreads();

  // prologue: layer-0 blocks publish V_0(1)
  if (l == 0) gen_V(vbuf, vflag, 0, s, 1, t);

  f32x16 acc_nb = {0,0,0,0,0,0,0,0,0,0,0,0,0,0,0,0};

  for (int d = 0; d <= 279; ++d) {
    const int k = d - l;

    // ---- (a) gates + LSTM update (uses acc_nb from previous diagonal) ----
    if (k >= 1 && k <= 255) {
      const uint16_t* hp = hstate + (((size_t)((k - 1) & 1) * NL_ + l) << 14);
      const uint16_t* ip = (l == 0)
          ? (emlp + ((size_t)k << 14))
          : (hstate + (((size_t)(k & 1) * NL_ + (l - 1)) << 14));
      f32x16 acc = {0,0,0,0,0,0,0,0,0,0,0,0,0,0,0,0};
#pragma unroll 4
      for (int kt = 0; kt < 16; ++kt) {
        short8v bv = *reinterpret_cast<const short8v*>(hp + bcol * 256 + kt * 16 + hi * 8);
        short8v av = *reinterpret_cast<const short8v*>(WAF + arow * 512 + ((kt * 32 + hi * 16) ^ aswz));
        acc = __builtin_amdgcn_mfma_f32_32x32x16_bf16(av, bv, acc, 0, 0, 0);
      }
#pragma unroll 4
      for (int kt = 0; kt < 16; ++kt) {
        short8v bv = *reinterpret_cast<const short8v*>(ip + bcol * 256 + kt * 16 + hi * 8);
        short8v av = *reinterpret_cast<const short8v*>(WAI + arow * 512 + ((kt * 32 + hi * 16) ^ aswz));
        acc = __builtin_amdgcn_mfma_f32_32x32x16_bf16(av, bv, acc, 0, 0, 0);
      }
      uint16_t* hd = hstate + (((size_t)(k & 1) * NL_ + l) << 14);
      const float* bf = biasf + l * 1024;
#pragma unroll
      for (int mq = 0; mq < 4; ++mq) {
        int mi = s * 32 + tm * 8 + mq * 2 + hi;
        float iv = acc[4 * mq + 0] + acc_nb[4 * mq + 0] + bf[mi];
        float fv = acc[4 * mq + 1] + acc_nb[4 * mq + 1] + bf[256 + mi];
        float gv = acc[4 * mq + 2] + acc_nb[4 * mq + 2] + bf[512 + mi];
        float ov = acc[4 * mq + 3] + acc_nb[4 * mq + 3] + bf[768 + mi];
        size_t cidx = ((size_t)l * 256 + mi) * 64 + bcol;
        float co = cstate[cidx];
        float cn = sigm(fv) * co + sigm(iv) * tanhf(gv);
        float hn = sigm(ov) * tanhf(cn);
        cstate[cidx] = cn;
        hd[bcol * 256 + mi] = f2bf(hn);
        if (l == NL_ - 1) hlast[((size_t)k << 14) + mi * 64 + bcol] = f2bf(hn);
      }
    }

    // ---- (b) arrive (release gates writes) ----
    bar_arrive(bar, grp, (uint32_t)(d + 1));

    // ---- (c) noise-GEMM for step k+1 (overlaps barrier latency) ----
    if (k + 1 >= 1 && k + 1 <= 255) {
      if (t == 0) {
        while (__hip_atomic_load(&vflag[l * 257 + (k + 1)], __ATOMIC_ACQUIRE,
                                 __HIP_MEMORY_SCOPE_AGENT) < 8u)
          __builtin_amdgcn_s_sleep(2);
      }
      __syncthreads();
      __threadfence();
      const uint16_t* V = vbuf + ((size_t)(((k + 1) % 3) * NL_ + l) << 14);
      f32x16 nbn = {0,0,0,0,0,0,0,0,0,0,0,0,0,0,0,0};
#pragma unroll 4
      for (int kt = 0; kt < 16; ++kt) {
        const float* wr = W_hh + ((size_t)l * 1024 + gi_a) * 256 + kt * 16 + hi * 8;
        float4 f0 = *reinterpret_cast<const float4*>(wr);
        float4 f1 = *reinterpret_cast<const float4*>(wr + 4);
        short8v av = pack8(f0, f1);
        short8v bv = *reinterpret_cast<const short8v*>(V + bcol * 256 + kt * 16 + hi * 8);
        nbn = __builtin_amdgcn_mfma_f32_32x32x16_bf16(av, bv, nbn, 0, 0, 0);
      }
      acc_nb = nbn;
    }

    // ---- (d) generate V chunk for step k+2 ----
    if (k + 2 >= 1 && k + 2 <= 255) gen_V(vbuf, vflag, l, s, k + 2, t);

    // ---- (e) wait ----
    bar_wait(bar, (uint32_t)(d + 1));
  }
}

// out[k][b][m] = Hlast[k] @ W_out^T + b_out ; out[0] = 0
__global__ __launch_bounds__(256) void k_final(const uint16_t* __restrict__ Hlast,
                                               const float* __restrict__ W_out,
                                               const float* __restrict__ b_out,
                                               float* __restrict__ out) {
  int k = blockIdx.x >> 2;
  int mc = blockIdx.x & 3;
  int lane = threadIdx.x & 63;
  int wv = threadIdx.x >> 6;
  int m0 = mc * 64 + wv * 16;
  float res[16];
  if (k == 0) {
#pragma unroll
    for (int mi = 0; mi < 16; ++mi) res[mi] = 0.0f;
  } else {
    float acc[16];
#pragma unroll
    for (int i = 0; i < 16; ++i) acc[i] = 0.0f;
    const uint16_t* src = Hlast + ((size_t)k << 14);
    for (int j = 0; j < L_; j += 4) {
      float a0 = bf2f(src[(j + 0) * B_ + lane]);
      float a1 = bf2f(src[(j + 1) * B_ + lane]);
      float a2 = bf2f(src[(j + 2) * B_ + lane]);
      float a3 = bf2f(src[(j + 3) * B_ + lane]);
#pragma unroll
      for (int mi = 0; mi < 16; ++mi) {
        float4 wt = *reinterpret_cast<const float4*>(&W_out[(size_t)(m0 + mi) * L_ + j]);
        float t = acc[mi];
        t = fmaf(a0, wt.x, t); t = fmaf(a1, wt.y, t);
        t = fmaf(a2, wt.z, t); t = fmaf(a3, wt.w, t);
        acc[mi] = t;
      }
    }
#pragma unroll
    for (int mi = 0; mi < 16; ++mi) res[mi] = acc[mi] + b_out[m0 + mi];
  }
  float* dst = out + ((size_t)k * B_ + lane) * L_ + m0;
#pragma unroll
  for (int v = 0; v < 4; ++v) {
    float4 t4 = make_float4(res[4 * v], res[4 * v + 1], res[4 * v + 2], res[4 * v + 3]);
    *reinterpret_cast<float4*>(&dst[4 * v]) = t4;
  }
}

// ------------------------------ launcher -----------------------------------
extern "C" void kernel_launch(void* const* d_in, const int* in_sizes, int n_in,
                              void* d_out, int out_size, void* d_ws, size_t ws_size,
                              hipStream_t stream) {
  const float* obsrv = (const float*)d_in[0];
  const float* z0    = (const float*)d_in[1];
  const float* W_emb = (const float*)d_in[2];
  const float* b_emb = (const float*)d_in[3];
  const float* Wx1   = (const float*)d_in[4];
  const float* bx1   = (const float*)d_in[5];
  const float* Wx2   = (const float*)d_in[6];
  const float* bx2   = (const float*)d_in[7];
  const float* Wx3   = (const float*)d_in[8];
  const float* bx3   = (const float*)d_in[9];
  const float* W_ih  = (const float*)d_in[10];
  const float* W_hh  = (const float*)d_in[11];
  const float* b_ih  = (const float*)d_in[12];
  const float* b_hh  = (const float*)d_in[13];
  const float* W_out = (const float*)d_in[14];
  const float* b_out = (const float*)d_in[15];
  float* out = (float*)d_out;
  unsigned char* ws = (unsigned char*)d_ws;

  if (ws_size < (size_t)WS_END) return;

  uint16_t* e1tmp   = (uint16_t*)(ws + SH_B);
  uint16_t* Hlast   = (uint16_t*)(ws + SH_B);
  uint16_t* E_mlp   = (uint16_t*)(ws + EMLP_B);
  uint16_t* h_state = (uint16_t*)(ws + HST_B);
  float*    c_state = (float*)(ws + CST_B);
  uint16_t* Wf      = (uint16_t*)(ws + WF_B);
  float*    biasf   = (float*)(ws + BIASF_B);
  uint16_t* vbuf    = (uint16_t*)(ws + VBUF_B);
  uint32_t* vflag   = (uint32_t*)(ws + VFLAG_B);
  uint32_t* bar     = (uint32_t*)(ws + BAR_B);

  k_init<<<(NL_ * L_ * B_) / 256, 256, 0, stream>>>(z0, h_state, c_state, vflag);
  k_wf<<<25 * 16, 256, 0, stream>>>(W_hh, W_emb, Wf);
  k_biasf<<<25 * 4, 256, 0, stream>>>(W_hh, b_emb, b_ih, b_hh, biasf);
  k_mlp1<<<255 * 4, 256, 0, stream>>>(obsrv, Wx1, bx1, e1tmp);
  k_mlp2<<<255, 256, 0, stream>>>(e1tmp, Wx2, bx2, Wx3, bx3, E_mlp);

  void* args[] = {(void*)&Wf, (void*)&W_ih, (void*)&W_hh, (void*)&biasf,
                  (void*)&h_state, (void*)&E_mlp, (void*)&c_state, (void*)&Hlast,
                  (void*)&vbuf, (void*)&vflag, (void*)&bar};
  hipLaunchCooperativeKernel((const void*)k_wave, dim3(NL_ * 8), dim3(512),
                             args, 0, stream);

  k_final<<<S_ * 4, 256, 0, stream>>>(Hlast, W_out, b_out, out);
}

// Round 6
// 16554.948 us; speedup vs baseline: 2.1460x; 2.1460x over previous
//
#include <hip/hip_runtime.h>
#include <hip/hip_cooperative_groups.h>
#include <stdint.h>

namespace cg = cooperative_groups;

// ---------------------------------------------------------------------------
// LIDM forward, round 6: r4 structure (cg::grid.sync) + 4-step-batched noise
// GEMM, bf16-prepacked W_hh (ws-size-gated), 8x-dedup V-gen via global vbuf,
// register-resident c-state, XCD-affine block mapping.
// ---------------------------------------------------------------------------
#define S_ 256
#define B_ 64
#define O_ 128
#define L_ 256
#define NL_ 25

typedef __attribute__((ext_vector_type(8))) short short8v;
typedef __attribute__((ext_vector_type(16))) float f32x16;

// ---- workspace byte offsets ----
#define SH_B    0u          // u16: e1 temp / Hlast [256][256][64]
#define EMLP_B  8388608u    // u16 [256][64][256]
#define HST_B   16777216u   // u16 [2][25][64][256]
#define WF_B    18415616u   // u16 [25][1024][256]
#define BIASF_B 31522816u   // f32 [25][1024]
#define VBUF_B  31625216u   // u16 [25][4][64][256]
#define WS_SMALL 34902016u
#define WN_B    34902016u   // u16 [25][8][32][128][8]  (prepacked bf16 W_hh)
#define WS_BIG  48009216u

// ---------------------------- helpers --------------------------------------
__device__ __forceinline__ uint16_t f2bf(float x) {
  uint32_t u = __float_as_uint(x);
  return (uint16_t)((u + 0x7fffu + ((u >> 16) & 1u)) >> 16);
}
__device__ __forceinline__ float bf2f(uint16_t u) {
  return __uint_as_float(((uint32_t)u) << 16);
}
__device__ __forceinline__ short8v pack8(float4 a, float4 b) {
  short8v w;
  w[0] = (short)f2bf(a.x); w[1] = (short)f2bf(a.y);
  w[2] = (short)f2bf(a.z); w[3] = (short)f2bf(a.w);
  w[4] = (short)f2bf(b.x); w[5] = (short)f2bf(b.y);
  w[6] = (short)f2bf(b.z); w[7] = (short)f2bf(b.w);
  return w;
}

__device__ __forceinline__ uint32_t rotl32(uint32_t v, int r) {
  return (v << r) | (v >> (32 - r));
}

__device__ __forceinline__ void tf2x32(uint32_t k0, uint32_t k1,
                                       uint32_t x0, uint32_t x1,
                                       uint32_t& o0, uint32_t& o1) {
  uint32_t ks2 = k0 ^ k1 ^ 0x1BD11BDAu;
  x0 += k0; x1 += k1;
  x0 += x1; x1 = rotl32(x1, 13); x1 ^= x0;
  x0 += x1; x1 = rotl32(x1, 15); x1 ^= x0;
  x0 += x1; x1 = rotl32(x1, 26); x1 ^= x0;
  x0 += x1; x1 = rotl32(x1,  6); x1 ^= x0;
  x0 += k1; x1 += ks2 + 1u;
  x0 += x1; x1 = rotl32(x1, 17); x1 ^= x0;
  x0 += x1; x1 = rotl32(x1, 29); x1 ^= x0;
  x0 += x1; x1 = rotl32(x1, 16); x1 ^= x0;
  x0 += x1; x1 = rotl32(x1, 24); x1 ^= x0;
  x0 += ks2; x1 += k0 + 2u;
  x0 += x1; x1 = rotl32(x1, 13); x1 ^= x0;
  x0 += x1; x1 = rotl32(x1, 15); x1 ^= x0;
  x0 += x1; x1 = rotl32(x1, 26); x1 ^= x0;
  x0 += x1; x1 = rotl32(x1,  6); x1 ^= x0;
  x0 += k0; x1 += k1 + 3u;
  x0 += x1; x1 = rotl32(x1, 17); x1 ^= x0;
  x0 += x1; x1 = rotl32(x1, 29); x1 ^= x0;
  x0 += x1; x1 = rotl32(x1, 16); x1 ^= x0;
  x0 += x1; x1 = rotl32(x1, 24); x1 ^= x0;
  x0 += k1; x1 += ks2 + 4u;
  x0 += x1; x1 = rotl32(x1, 13); x1 ^= x0;
  x0 += x1; x1 = rotl32(x1, 15); x1 ^= x0;
  x0 += x1; x1 = rotl32(x1, 26); x1 ^= x0;
  x0 += x1; x1 = rotl32(x1,  6); x1 ^= x0;
  o0 = x0 + ks2; o1 = x1 + k0 + 5u;
}

__device__ __forceinline__ void step_keys(int k, uint32_t& kh0, uint32_t& kh1,
                                          uint32_t& kx0, uint32_t& kx1) {
  uint32_t f0, f1;
  tf2x32(0u, 42u, 0u, (uint32_t)k, f0, f1);
  tf2x32(f0, f1, 0u, 0u, kh0, kh1);
  tf2x32(f0, f1, 0u, 1u, kx0, kx1);
}

__device__ __forceinline__ uint32_t rbits(uint32_t key0, uint32_t key1,
                                          uint32_t i) {
  uint32_t b0, b1;
  tf2x32(key0, key1, 0u, i, b0, b1);
  return b0 ^ b1;
}

__device__ __forceinline__ float u32_to_normal(uint32_t bits) {
  const float lo = __uint_as_float(0xBF7FFFFFu);
  float f = __uint_as_float((bits >> 9) | 0x3F800000u) - 1.0f;
  float u = f * 2.0f + lo;
  u = fmaxf(lo, u);
  float x = u;
  float w = -log1pf(-x * x);
  float p;
  if (w < 5.0f) {
    w -= 2.5f;
    p =            2.81022636e-08f;
    p = fmaf(p, w, 3.43273939e-07f);
    p = fmaf(p, w, -3.5233877e-06f);
    p = fmaf(p, w, -4.39150654e-06f);
    p = fmaf(p, w, 0.00021858087f);
    p = fmaf(p, w, -0.00125372503f);
    p = fmaf(p, w, -0.00417768164f);
    p = fmaf(p, w, 0.246640727f);
    p = fmaf(p, w, 1.50140941f);
  } else {
    w = sqrtf(w) - 3.0f;
    p =            -0.000200214257f;
    p = fmaf(p, w, 0.000100950558f);
    p = fmaf(p, w, 0.00134934322f);
    p = fmaf(p, w, -0.00367342844f);
    p = fmaf(p, w, 0.00573950773f);
    p = fmaf(p, w, -0.0076224613f);
    p = fmaf(p, w, 0.00943887047f);
    p = fmaf(p, w, 1.00167406f);
    p = fmaf(p, w, 2.83297682f);
  }
  return __uint_as_float(0x3FB504F3u) * (p * x);
}

__device__ __forceinline__ float sigm(float x) { return 1.0f / (1.0f + expf(-x)); }

// ------------------------------- prep kernels ------------------------------
__global__ __launch_bounds__(256) void k_init(const float* __restrict__ z0,
                                              uint16_t* __restrict__ hs0) {
  int idx = blockIdx.x * 256 + threadIdx.x;
  hs0[idx] = f2bf(z0[idx]);
}

__global__ __launch_bounds__(256) void k_wf(const float* __restrict__ Whh,
                                            const float* __restrict__ Wemb,
                                            uint16_t* __restrict__ Wf) {
  __shared__ float Bs[32][256];
  int l = blockIdx.x >> 4, rt = blockIdx.x & 15;
  int j = threadIdx.x;
  float acc[64];
#pragma unroll
  for (int r = 0; r < 64; ++r) acc[r] = 0.0f;
  const float* Abase = Whh + ((size_t)l * 1024 + rt * 64) * 256;
  for (int m0 = 0; m0 < 256; m0 += 32) {
    __syncthreads();
    {
      int rr = threadIdx.x >> 3, cseg = threadIdx.x & 7;
      const float* src = Wemb + (size_t)(m0 + rr) * 256 + cseg * 32;
      float* dst = &Bs[rr][cseg * 32];
#pragma unroll
      for (int q = 0; q < 8; ++q)
        reinterpret_cast<float4*>(dst)[q] = reinterpret_cast<const float4*>(src)[q];
    }
    __syncthreads();
    for (int mm = 0; mm < 32; ++mm) {
      float bj = Bs[mm][j];
      const float* Acol = Abase + m0 + mm;
#pragma unroll
      for (int r = 0; r < 64; ++r) acc[r] = fmaf(Acol[r * 256], bj, acc[r]);
    }
  }
  for (int r = 0; r < 64; ++r)
    Wf[((size_t)l * 1024 + rt * 64 + r) * 256 + j] = f2bf(acc[r]);
}

__global__ __launch_bounds__(256) void k_biasf(const float* __restrict__ Whh,
                                               const float* __restrict__ bemb,
                                               const float* __restrict__ bih,
                                               const float* __restrict__ bhh,
                                               float* __restrict__ biasf) {
  int l = blockIdx.x >> 2;
  int gi = (blockIdx.x & 3) * 256 + threadIdx.x;
  const float* row = Whh + ((size_t)l * 1024 + gi) * 256;
  float a = 0.0f;
  for (int m = 0; m < 256; ++m) a = fmaf(row[m], bemb[m], a);
  biasf[l * 1024 + gi] = a + bih[l * 1024 + gi] + bhh[l * 1024 + gi];
}

// prepack W_hh -> bf16 Wn[l][s][c2=kt*2+hi][r 0..127][8 elems]
__global__ __launch_bounds__(256) void k_wn(const float* __restrict__ Whh,
                                            uint16_t* __restrict__ Wn) {
  int l = blockIdx.x >> 3, s = blockIdx.x & 7;
  uint16_t* base = Wn + ((size_t)(l * 8 + s) << 15);
  for (int it = 0; it < 16; ++it) {
    int c = it * 256 + threadIdx.x;   // 0..4095
    int c2 = c >> 7;
    int r = c & 127;
    int gi = (r & 3) * 256 + s * 32 + (r >> 5) * 8 + ((r >> 2) & 7);
    const float* src = Whh + ((size_t)l * 1024 + gi) * 256 + c2 * 8;
    float4 f0 = *reinterpret_cast<const float4*>(src);
    float4 f1 = *reinterpret_cast<const float4*>(src + 4);
    *reinterpret_cast<short8v*>(base + (size_t)c * 8) = pack8(f0, f1);
  }
}

__global__ __launch_bounds__(256) void k_mlp1(const float* __restrict__ obsrv,
                                              const float* __restrict__ Wx1,
                                              const float* __restrict__ bx1,
                                              uint16_t* __restrict__ e1out) {
  int k = 1 + (blockIdx.x >> 2);
  int jc = blockIdx.x & 3;
  int lane = threadIdx.x & 63;
  int wv = threadIdx.x >> 6;
  int j0 = jc * 64 + wv * 16;
  const float* xrow = obsrv + ((size_t)k * B_ + lane) * O_;
  float acc[16];
#pragma unroll
  for (int i = 0; i < 16; ++i) acc[i] = 0.0f;
  for (int o = 0; o < O_; o += 4) {
    float4 a = *reinterpret_cast<const float4*>(&xrow[o]);
#pragma unroll
    for (int mi = 0; mi < 16; ++mi) {
      float4 wt = *reinterpret_cast<const float4*>(&Wx1[(size_t)(j0 + mi) * O_ + o]);
      float t = acc[mi];
      t = fmaf(a.x, wt.x, t); t = fmaf(a.y, wt.y, t);
      t = fmaf(a.z, wt.z, t); t = fmaf(a.w, wt.w, t);
      acc[mi] = t;
    }
  }
  uint16_t* dst = e1out + (size_t)k * L_ * B_;
#pragma unroll
  for (int mi = 0; mi < 16; ++mi) {
    float v = acc[mi] + bx1[j0 + mi];
    dst[(j0 + mi) * B_ + lane] = f2bf(fmaxf(v, 0.0f));
  }
}

__global__ __launch_bounds__(256) void k_mlp2(const uint16_t* __restrict__ e1buf,
                                              const float* __restrict__ Wx2,
                                              const float* __restrict__ bx2,
                                              const float* __restrict__ Wx3,
                                              const float* __restrict__ bx3,
                                              uint16_t* __restrict__ E_mlp) {
  __shared__ float e2s[L_ * B_];
  int k = 1 + blockIdx.x;
  int lane = threadIdx.x & 63;
  int wv = threadIdx.x >> 6;
  const uint16_t* e1 = e1buf + (size_t)k * L_ * B_;

  for (int rep = 0; rep < 4; ++rep) {
    int m0 = rep * 64 + wv * 16;
    float acc[16];
#pragma unroll
    for (int i = 0; i < 16; ++i) acc[i] = 0.0f;
    for (int j = 0; j < L_; j += 4) {
      float a0 = bf2f(e1[(j + 0) * B_ + lane]);
      float a1 = bf2f(e1[(j + 1) * B_ + lane]);
      float a2 = bf2f(e1[(j + 2) * B_ + lane]);
      float a3 = bf2f(e1[(j + 3) * B_ + lane]);
#pragma unroll
      for (int mi = 0; mi < 16; ++mi) {
        float4 wt = *reinterpret_cast<const float4*>(&Wx2[(size_t)(m0 + mi) * L_ + j]);
        float t = acc[mi];
        t = fmaf(a0, wt.x, t); t = fmaf(a1, wt.y, t);
        t = fmaf(a2, wt.z, t); t = fmaf(a3, wt.w, t);
        acc[mi] = t;
      }
    }
#pragma unroll
    for (int mi = 0; mi < 16; ++mi) {
      float v = acc[mi] + bx2[m0 + mi];
      e2s[(m0 + mi) * B_ + lane] = fmaxf(v, 0.0f);
    }
  }
  __syncthreads();

  uint32_t kh0, kh1, kx0, kx1;
  step_keys(k, kh0, kh1, kx0, kx1);
  const float sa = sqrtf(0.9f);

  for (int rep = 0; rep < 4; ++rep) {
    int m0 = rep * 64 + wv * 16;
    float acc[16];
#pragma unroll
    for (int i = 0; i < 16; ++i) acc[i] = 0.0f;
    for (int j = 0; j < L_; j += 4) {
      float a0 = e2s[(j + 0) * B_ + lane];
      float a1 = e2s[(j + 1) * B_ + lane];
      float a2 = e2s[(j + 2) * B_ + lane];
      float a3 = e2s[(j + 3) * B_ + lane];
#pragma unroll
      for (int mi = 0; mi < 16; ++mi) {
        float4 wt = *reinterpret_cast<const float4*>(&Wx3[(size_t)(m0 + mi) * L_ + j]);
        float t = acc[mi];
        t = fmaf(a0, wt.x, t); t = fmaf(a1, wt.y, t);
        t = fmaf(a2, wt.z, t); t = fmaf(a3, wt.w, t);
        acc[mi] = t;
      }
    }
    uint16_t tmp[16];
#pragma unroll
    for (int mi = 0; mi < 16; ++mi) {
      int m = m0 + mi;
      float nz = u32_to_normal(rbits(kx0, kx1, (uint32_t)(lane * L_ + m)));
      tmp[mi] = f2bf(sa * (acc[mi] + bx3[m]) + 0.1f * nz);
    }
    uint16_t* dst = E_mlp + ((size_t)k * B_ + lane) * L_ + m0;
    *reinterpret_cast<uint4*>(dst) = *reinterpret_cast<const uint4*>(&tmp[0]);
    *reinterpret_cast<uint4*>(dst + 8) = *reinterpret_cast<const uint4*>(&tmp[8]);
  }
}

// ------------------------------ wavefront ----------------------------------
// 200 blocks x 512 thr; XCD-affine remap; LDS 131072 B; c-state in registers.
__global__ __launch_bounds__(512, 1) void k_wave(
    const uint16_t* __restrict__ Wf, const float* __restrict__ W_ih,
    const float* __restrict__ W_hh, const uint16_t* __restrict__ Wn,
    const float* __restrict__ biasf, uint16_t* __restrict__ hstate,
    const uint16_t* __restrict__ emlp, uint16_t* __restrict__ hlast,
    uint16_t* __restrict__ vbuf, int useWn) {
  cg::grid_group grid = cg::this_grid();
  __shared__ __align__(16) unsigned char WAF[65536];
  __shared__ __align__(16) unsigned char WAI[65536];

  // XCD-affine: consecutive-bid round-robin -> same-layer blocks co-XCD
  const int slot = (blockIdx.x & 7) * 25 + (blockIdx.x >> 3);
  const int l = slot >> 3;
  const int s = slot & 7;
  const int t = threadIdx.x;
  const int lane = t & 63;
  const int wid = t >> 6;
  const int lo5 = lane & 31;
  const int hi = lane >> 5;
  const int tm = wid >> 1;
  const int tn = wid & 1;
  const int bcol = tn * 32 + lo5;
  const int arow = tm * 32 + lo5;
  const int aswz = (arow & 7) << 4;
  const int gi_a = (arow & 3) * 256 + s * 32 + (arow >> 5) * 8 + ((arow >> 2) & 7);

  for (int it = 0; it < 8; ++it) {
    int c = it * 512 + t;
    int r = c >> 5, cc = c & 31;
    int gi = (r & 3) * 256 + s * 32 + (r >> 5) * 8 + ((r >> 2) & 7);
    uint4 v = *reinterpret_cast<const uint4*>(Wf + ((size_t)l * 1024 + gi) * 256 + cc * 8);
    *reinterpret_cast<uint4*>(WAF + r * 512 + ((cc * 16) ^ ((r & 7) << 4))) = v;
  }
  for (int it = 0; it < 8; ++it) {
    int c = it * 512 + t;
    int r = c >> 5, cc = c & 31;
    int gi = (r & 3) * 256 + s * 32 + (r >> 5) * 8 + ((r >> 2) & 7);
    const float* sr = W_ih + ((size_t)l * 1024 + gi) * 256 + cc * 8;
    float4 f0 = *reinterpret_cast<const float4*>(sr);
    float4 f1 = *reinterpret_cast<const float4*>(sr + 4);
    *reinterpret_cast<short8v*>(WAI + r * 512 + ((cc * 16) ^ ((r & 7) << 4))) = pack8(f0, f1);
  }
  __syncthreads();

  f32x16 nbt[4];
#pragma unroll
  for (int q = 0; q < 4; ++q)
    nbt[q] = f32x16{0,0,0,0,0,0,0,0,0,0,0,0,0,0,0,0};
  float cst[4] = {0.0f, 0.0f, 0.0f, 0.0f};

  // V-gen constants: this block writes half of panel j=s>>1 (b-range by s&1)
  const int vj = s >> 1;
  const int vb = 32 * (s & 1) + (t >> 4);
  const int vjseg = (t & 15) * 16;

  for (int d = 0; d <= 279; ++d) {
    const int k = d - l;

    // ---- cooperative V-gen for steps k+1..k+4 (once per 4 diags) ----
    if (k >= 0 && k <= 252 && (k & 3) == 0) {
#pragma unroll
      for (int st = 0; st < 4; ++st) {
        uint32_t kh0, kh1, kx0, kx1;
        step_keys(k + 1 + st, kh0, kh1, kx0, kx1);
        uint32_t ib = ((uint32_t)(l * 64 + vb)) * 256 + (uint32_t)vjseg;
        uint16_t v[16];
#pragma unroll
        for (int q = 0; q < 16; ++q)
          v[q] = f2bf(0.1f * u32_to_normal(rbits(kh0, kh1, ib + q)));
        uint16_t* dst = vbuf + (((size_t)(l * 4 + vj) << 14) + vb * 256 + vjseg);
        // note: panel index is st's panel only when vj==st's... each block
        // writes its fixed half-panel (l, vj) for step k+1+vj? NO — panel per
        // step: panel j holds step k+1+j; this block contributes to panel vj
        // only for st == vj.
        if (st == vj) {
          *reinterpret_cast<uint4*>(dst) = *reinterpret_cast<const uint4*>(&v[0]);
          *reinterpret_cast<uint4*>(dst + 8) = *reinterpret_cast<const uint4*>(&v[8]);
        }
      }
    }

    if (k >= 1 && k <= 255) {
      // ---- batched noise GEMM: steps k..k+3 (once per 4 diags) ----
      if ((k & 3) == 1) {
#pragma unroll
        for (int st = 0; st < 4; ++st) {
          f32x16 nbn = {0,0,0,0,0,0,0,0,0,0,0,0,0,0,0,0};
          const uint16_t* V = vbuf + ((size_t)(l * 4 + st) << 14);
          if (useWn) {
            const uint16_t* wb = Wn + ((size_t)(l * 8 + s) << 15);
#pragma unroll 4
            for (int kt = 0; kt < 16; ++kt) {
              short8v av = *reinterpret_cast<const short8v*>(
                  wb + ((size_t)((kt * 2 + hi) * 128 + arow)) * 8);
              short8v bv = *reinterpret_cast<const short8v*>(V + bcol * 256 + kt * 16 + hi * 8);
              nbn = __builtin_amdgcn_mfma_f32_32x32x16_bf16(av, bv, nbn, 0, 0, 0);
            }
          } else {
#pragma unroll 4
            for (int kt = 0; kt < 16; ++kt) {
              const float* wr = W_hh + ((size_t)l * 1024 + gi_a) * 256 + kt * 16 + hi * 8;
              float4 f0 = *reinterpret_cast<const float4*>(wr);
              float4 f1 = *reinterpret_cast<const float4*>(wr + 4);
              short8v av = pack8(f0, f1);
              short8v bv = *reinterpret_cast<const short8v*>(V + bcol * 256 + kt * 16 + hi * 8);
              nbn = __builtin_amdgcn_mfma_f32_32x32x16_bf16(av, bv, nbn, 0, 0, 0);
            }
          }
          nbt[st] = nbn;
        }
      }

      // ---- gates + LSTM update (noise from nbt[0]) ----
      const uint16_t* hp = hstate + (((size_t)((k - 1) & 1) * NL_ + l) << 14);
      const uint16_t* ip = (l == 0)
          ? (emlp + ((size_t)k << 14))
          : (hstate + (((size_t)(k & 1) * NL_ + (l - 1)) << 14));
      f32x16 acc = {0,0,0,0,0,0,0,0,0,0,0,0,0,0,0,0};
#pragma unroll 4
      for (int kt = 0; kt < 16; ++kt) {
        short8v bv = *reinterpret_cast<const short8v*>(hp + bcol * 256 + kt * 16 + hi * 8);
        short8v av = *reinterpret_cast<const short8v*>(WAF + arow * 512 + ((kt * 32 + hi * 16) ^ aswz));
        acc = __builtin_amdgcn_mfma_f32_32x32x16_bf16(av, bv, acc, 0, 0, 0);
      }
#pragma unroll 4
      for (int kt = 0; kt < 16; ++kt) {
        short8v bv = *reinterpret_cast<const short8v*>(ip + bcol * 256 + kt * 16 + hi * 8);
        short8v av = *reinterpret_cast<const short8v*>(WAI + arow * 512 + ((kt * 32 + hi * 16) ^ aswz));
        acc = __builtin_amdgcn_mfma_f32_32x32x16_bf16(av, bv, acc, 0, 0, 0);
      }
      uint16_t* hd = hstate + (((size_t)(k & 1) * NL_ + l) << 14);
      const float* bf = biasf + l * 1024;
#pragma unroll
      for (int mq = 0; mq < 4; ++mq) {
        int mi = s * 32 + tm * 8 + mq * 2 + hi;
        float iv = acc[4 * mq + 0] + nbt[0][4 * mq + 0] + bf[mi];
        float fv = acc[4 * mq + 1] + nbt[0][4 * mq + 1] + bf[256 + mi];
        float gv = acc[4 * mq + 2] + nbt[0][4 * mq + 2] + bf[512 + mi];
        float ov = acc[4 * mq + 3] + nbt[0][4 * mq + 3] + bf[768 + mi];
        float cn = sigm(fv) * cst[mq] + sigm(iv) * tanhf(gv);
        float hn = sigm(ov) * tanhf(cn);
        cst[mq] = cn;
        hd[bcol * 256 + mi] = f2bf(hn);
        if (l == NL_ - 1) hlast[((size_t)k << 14) + mi * 64 + bcol] = f2bf(hn);
      }
      // rotate noise pipeline (static indices only)
      nbt[0] = nbt[1]; nbt[1] = nbt[2]; nbt[2] = nbt[3];
    }

    grid.sync();
  }
}

// out[k][b][m] = Hlast[k] @ W_out^T + b_out ; out[0] = 0
__global__ __launch_bounds__(256) void k_final(const uint16_t* __restrict__ Hlast,
                                               const float* __restrict__ W_out,
                                               const float* __restrict__ b_out,
                                               float* __restrict__ out) {
  int k = blockIdx.x >> 2;
  int mc = blockIdx.x & 3;
  int lane = threadIdx.x & 63;
  int wv = threadIdx.x >> 6;
  int m0 = mc * 64 + wv * 16;
  float res[16];
  if (k == 0) {
#pragma unroll
    for (int mi = 0; mi < 16; ++mi) res[mi] = 0.0f;
  } else {
    float acc[16];
#pragma unroll
    for (int i = 0; i < 16; ++i) acc[i] = 0.0f;
    const uint16_t* src = Hlast + ((size_t)k << 14);
    for (int j = 0; j < L_; j += 4) {
      float a0 = bf2f(src[(j + 0) * B_ + lane]);
      float a1 = bf2f(src[(j + 1) * B_ + lane]);
      float a2 = bf2f(src[(j + 2) * B_ + lane]);
      float a3 = bf2f(src[(j + 3) * B_ + lane]);
#pragma unroll
      for (int mi = 0; mi < 16; ++mi) {
        float4 wt = *reinterpret_cast<const float4*>(&W_out[(size_t)(m0 + mi) * L_ + j]);
        float t = acc[mi];
        t = fmaf(a0, wt.x, t); t = fmaf(a1, wt.y, t);
        t = fmaf(a2, wt.z, t); t = fmaf(a3, wt.w, t);
        acc[mi] = t;
      }
    }
#pragma unroll
    for (int mi = 0; mi < 16; ++mi) res[mi] = acc[mi] + b_out[m0 + mi];
  }
  float* dst = out + ((size_t)k * B_ + lane) * L_ + m0;
#pragma unroll
  for (int v = 0; v < 4; ++v) {
    float4 t4 = make_float4(res[4 * v], res[4 * v + 1], res[4 * v + 2], res[4 * v + 3]);
    *reinterpret_cast<float4*>(&dst[4 * v]) = t4;
  }
}

// ------------------------------ launcher -----------------------------------
extern "C" void kernel_launch(void* const* d_in, const int* in_sizes, int n_in,
                              void* d_out, int out_size, void* d_ws, size_t ws_size,
                              hipStream_t stream) {
  const float* obsrv = (const float*)d_in[0];
  const float* z0    = (const float*)d_in[1];
  const float* W_emb = (const float*)d_in[2];
  const float* b_emb = (const float*)d_in[3];
  const float* Wx1   = (const float*)d_in[4];
  const float* bx1   = (const float*)d_in[5];
  const float* Wx2   = (const float*)d_in[6];
  const float* bx2   = (const float*)d_in[7];
  const float* Wx3   = (const float*)d_in[8];
  const float* bx3   = (const float*)d_in[9];
  const float* W_ih  = (const float*)d_in[10];
  const float* W_hh  = (const float*)d_in[11];
  const float* b_ih  = (const float*)d_in[12];
  const float* b_hh  = (const float*)d_in[13];
  const float* W_out = (const float*)d_in[14];
  const float* b_out = (const float*)d_in[15];
  float* out = (float*)d_out;
  unsigned char* ws = (unsigned char*)d_ws;

  if (ws_size < (size_t)WS_SMALL) return;
  const int useWn = ws_size >= (size_t)WS_BIG ? 1 : 0;

  uint16_t* e1tmp   = (uint16_t*)(ws + SH_B);
  uint16_t* Hlast   = (uint16_t*)(ws + SH_B);
  uint16_t* E_mlp   = (uint16_t*)(ws + EMLP_B);
  uint16_t* h_state = (uint16_t*)(ws + HST_B);
  uint16_t* Wf      = (uint16_t*)(ws + WF_B);
  float*    biasf   = (float*)(ws + BIASF_B);
  uint16_t* vbuf    = (uint16_t*)(ws + VBUF_B);
  uint16_t* Wn      = (uint16_t*)(ws + WN_B);

  k_init<<<(NL_ * L_ * B_) / 256, 256, 0, stream>>>(z0, h_state);
  k_wf<<<25 * 16, 256, 0, stream>>>(W_hh, W_emb, Wf);
  k_biasf<<<25 * 4, 256, 0, stream>>>(W_hh, b_emb, b_ih, b_hh, biasf);
  if (useWn) k_wn<<<25 * 8, 256, 0, stream>>>(W_hh, Wn);
  k_mlp1<<<255 * 4, 256, 0, stream>>>(obsrv, Wx1, bx1, e1tmp);
  k_mlp2<<<255, 256, 0, stream>>>(e1tmp, Wx2, bx2, Wx3, bx3, E_mlp);

  void* args[] = {(void*)&Wf, (void*)&W_ih, (void*)&W_hh, (void*)&Wn,
                  (void*)&biasf, (void*)&h_state, (void*)&E_mlp, (void*)&Hlast,
                  (void*)&vbuf, (void*)&useWn};
  hipLaunchCooperativeKernel((const void*)k_wave, dim3(NL_ * 8), dim3(512),
                             args, 0, stream);

  k_final<<<S_ * 4, 256, 0, stream>>>(Hlast, W_out, b_out, out);
}